// Round 3
// baseline (872.545 us; speedup 1.0000x reference)
//
#include <hip/hip_runtime.h>
#include <math.h>

typedef unsigned short u16;
typedef __attribute__((ext_vector_type(8))) short short8;
typedef __attribute__((ext_vector_type(4))) float floatx4;

__device__ __forceinline__ u16 f2bf(float f) {
    union { float f; unsigned u; } v; v.f = f;
    unsigned r = v.u + 0x7fffu + ((v.u >> 16) & 1u);
    return (u16)(r >> 16);
}

struct WPtrs {
    const float* w1[5];
    const float* w2[5];
};

// ---------------- prep (unchanged layout) ----------------
// W1t: [head][n][k-chunks swizzled]: element (h,n,k) at h*65536 + n*256 + ((kc ^ (n&31))<<3) + (k&7)
// W2t: [112][256] rows: mask@0(16), pos@16, scl@32, rot@48, shs@64(48); W2t[roff+n2][k]=w2[k*od+n2]
// enc: 64 bf16 relu'd time positional encoding
__global__ void prep_weights(WPtrs p, const float* __restrict__ te,
                             u16* __restrict__ W1t, u16* __restrict__ W2t,
                             u16* __restrict__ enc)
{
    const int bid = blockIdx.x;
    const int tid = threadIdx.x;
    if (bid < 80) {
        __shared__ float tile[64 * 65];
        int h = bid / 16, t = bid % 16;
        int k0 = (t / 4) * 64, n0 = (t % 4) * 64;
        int nn = tid & 63, g = tid >> 6;
        const float* w1 = p.w1[h];
#pragma unroll
        for (int rep = 0; rep < 16; ++rep) {
            int kl = g * 16 + rep;
            int k = k0 + kl, nidx = n0 + nn;
            float v = (k < 255 && nidx < 255) ? w1[k * 255 + nidx] : 0.0f;
            tile[kl * 65 + nn] = v;
        }
        __syncthreads();
#pragma unroll
        for (int i = 0; i < 2; ++i) {
            int c = tid * 2 + i;            // 0..511
            int nl = c >> 3, kcl = c & 7;
            int n = n0 + nl;
            int kcg = (k0 >> 3) + kcl;
            short8 sv;
#pragma unroll
            for (int j = 0; j < 8; ++j)
                sv[j] = (short)f2bf(tile[(kcl * 8 + j) * 65 + nl]);
            *(short8*)(W1t + h * 65536 + n * 256 + (((kcg ^ (n & 31))) << 3)) = sv;
        }
    } else if (bid < 192) {
        int row = bid - 80;               // 0..111
        int h, roff, od;
        if (row < 16)      { h = 0; roff = 0;  od = 1; }
        else if (row < 32) { h = 1; roff = 16; od = 3; }
        else if (row < 48) { h = 2; roff = 32; od = 3; }
        else if (row < 64) { h = 3; roff = 48; od = 4; }
        else               { h = 4; roff = 64; od = 48; }
        int n2 = row - roff;
        int k = tid;
        float v = (k < 255 && n2 < od) ? p.w2[h][k * od + n2] : 0.0f;
        W2t[row * 256 + k] = f2bf(v);
    } else {
        if (tid < 64) {
            float t = te[0];
            float fi = (float)(tid & ~1);
            float freq = powf(10000.0f, fi * (1.0f / 32.0f));
            float a = t / freq;
            float v = (tid & 1) ? cosf(a) : sinf(a);
            enc[tid] = f2bf(fmaxf(v, 0.0f));
        }
    }
}

// ---------------- fused everything: gather + 5-head MLP, no LDS W1, no barriers ----------------
struct FusedArgs {
    const u16* W1t; const u16* W2t; const u16* enc;
    const float* b1[5]; const float* b2[5];
    const float* opa; const float* shs; const float* te; const float* sem;
    const float* pt;  const float* scl; const float* rot; const float* dxp;
    float* out; int n;
};

// build one 8-col chunk of x = relu(concat) for a row (same semantics as old build_x)
__device__ __forceinline__ short8 gather8(const FusedArgs& A, const u16* encS, int row, int c0)
{
    short8 sv;
    if (c0 >= 64 && c0 <= 176) {
        // pure semantic_feature fast path (cols within [59,187))
        const float* s = A.sem + (size_t)row * 128 + (c0 - 59);
        float4 a = *(const float4*)(s);
        float4 b = *(const float4*)(s + 4);
        sv[0] = (short)f2bf(fmaxf(a.x, 0.f)); sv[1] = (short)f2bf(fmaxf(a.y, 0.f));
        sv[2] = (short)f2bf(fmaxf(a.z, 0.f)); sv[3] = (short)f2bf(fmaxf(a.w, 0.f));
        sv[4] = (short)f2bf(fmaxf(b.x, 0.f)); sv[5] = (short)f2bf(fmaxf(b.y, 0.f));
        sv[6] = (short)f2bf(fmaxf(b.z, 0.f)); sv[7] = (short)f2bf(fmaxf(b.w, 0.f));
    } else if (c0 >= 192) {
        // pure time-positional-encoding chunk (already relu'd bf16); c==255 is pad 0
#pragma unroll
        for (int j = 0; j < 8; ++j) {
            int c = c0 + j;
            sv[j] = (c < 255) ? (short)encS[c - 191] : (short)0;
        }
    } else {
#pragma unroll
        for (int j = 0; j < 8; ++j) {
            int c = c0 + j;
            float v;
            if (c < 3)        v = A.pt[row * 3 + c];
            else if (c < 7)   v = A.rot[row * 4 + (c - 3)];
            else if (c < 10)  v = A.scl[row * 3 + (c - 7)];
            else if (c < 11)  v = A.opa[row];
            else if (c < 59)  v = A.shs[(size_t)row * 48 + (c - 11)];
            else if (c < 187) v = A.sem[(size_t)row * 128 + (c - 59)];
            else if (c < 190) v = A.dxp[row * 3 + (c - 187)];
            else if (c < 191) v = A.te[row];
            else { sv[j] = (short)encS[c - 191]; continue; }   // c==191 (enc[0], relu'd)
            sv[j] = (short)f2bf(fmaxf(v, 0.0f));
        }
    }
    return sv;
}

// layer1 half: h1 cols [part*128, part*128+128), W1 frags streamed from global (L2-hot).
// acc[ct][t] lane(q,ln) reg r: h1pre[c = part*128 + ct*16 + q*4 + r][row = r0 + 16t + ln]
__device__ __forceinline__ void layer1_part(const short8 (&xf)[2][8], const u16* __restrict__ W1g,
                                            int part, int q, int ln, floatx4 (&acc)[8][2])
{
#pragma unroll
    for (int ct = 0; ct < 8; ++ct) {
        acc[ct][0] = (floatx4){0.f, 0.f, 0.f, 0.f};
        acc[ct][1] = (floatx4){0.f, 0.f, 0.f, 0.f};
    }
#pragma unroll
    for (int kk = 0; kk < 8; ++kk) {
#pragma unroll
        for (int ct = 0; ct < 8; ++ct) {
            int nidx = part * 128 + ct * 16 + ln;
            int sw = (kk * 4 + q) ^ (nidx & 31);
            short8 wf = *(const short8*)(W1g + nidx * 256 + (sw << 3));
            acc[ct][0] = __builtin_amdgcn_mfma_f32_16x16x32_bf16(wf, xf[0][kk], acc[ct][0], 0, 0, 0);
            acc[ct][1] = __builtin_amdgcn_mfma_f32_16x16x32_bf16(wf, xf[1][kk], acc[ct][1], 0, 0, 0);
        }
    }
}

// layer2 half: bias+relu acc in place, then accumulate acc2 over this half's 128 k (ks 0..3).
template<int MT>
__device__ __forceinline__ void layer2_part(floatx4 (&acc)[8][2], const float* __restrict__ b1h,
                                            const u16* __restrict__ w2th, int part, int q, int ln,
                                            floatx4 (&acc2)[3][2])
{
#pragma unroll
    for (int ct = 0; ct < 8; ++ct) {
        // b1 has exactly 255 floats; the (part==1, ct==7, q==3) quad would read b1[255] OOB.
        // Load that tail quad as 3 scalars + 0 (h1 col 255 is the zero pad column).
        floatx4 b4;
        if (part == 1 && ct == 7) {
            if (q == 3) {
                b4.x = b1h[252]; b4.y = b1h[253]; b4.z = b1h[254]; b4.w = 0.f;
            } else {
                b4 = *(const floatx4*)(b1h + 240 + q * 4);
            }
        } else {
            b4 = *(const floatx4*)(b1h + part * 128 + ct * 16 + q * 4);
        }
#pragma unroll
        for (int t = 0; t < 2; ++t) {
            floatx4 v = acc[ct][t];
            v.x = fmaxf(v.x + b4.x, 0.f);
            v.y = fmaxf(v.y + b4.y, 0.f);
            v.z = fmaxf(v.z + b4.z, 0.f);
            v.w = fmaxf(v.w + b4.w, 0.f);
            acc[ct][t] = v;
        }
    }
    if (part == 0) {
#pragma unroll
        for (int mt = 0; mt < MT; ++mt) {
            acc2[mt][0] = (floatx4){0.f, 0.f, 0.f, 0.f};
            acc2[mt][1] = (floatx4){0.f, 0.f, 0.f, 0.f};
        }
    }
#pragma unroll
    for (int ks = 0; ks < 4; ++ks) {
        int ksg = part * 4 + ks;
        short8 a2[MT];
#pragma unroll
        for (int mt = 0; mt < MT; ++mt)
            a2[mt] = *(const short8*)(w2th + (mt * 16 + ln) * 256 + ksg * 32 + q * 8);
#pragma unroll
        for (int t = 0; t < 2; ++t) {
            short8 bfrag;
#pragma unroll
            for (int j = 0; j < 8; ++j) {
                int idx = (((q * 2 + (j >> 2)) & 3) << 4) | ln;
                float v0 = __shfl(acc[ks * 2 + 0][t][j & 3], idx, 64);
                float v1 = __shfl(acc[ks * 2 + 1][t][j & 3], idx, 64);
                float v = (q >> 1) ? v1 : v0;
                bfrag[j] = (short)f2bf(v);
            }
#pragma unroll
            for (int mt = 0; mt < MT; ++mt)
                acc2[mt][t] = __builtin_amdgcn_mfma_f32_16x16x32_bf16(a2[mt], bfrag, acc2[mt][t], 0, 0, 0);
        }
    }
}

__global__ __launch_bounds__(256, 2) void fused_all(FusedArgs A)
{
    __shared__ u16 encS[64];
    const int tid = threadIdx.x;
    if (tid < 64) encS[tid] = A.enc[tid];
    __syncthreads();   // only barrier in the kernel

    const int n = A.n;
    const int wid = blockIdx.x * 4 + (tid >> 6);
    const int lane = tid & 63;
    const int q = lane >> 4, ln = lane & 15;
    const int r0 = wid * 32;
    if (r0 >= n) return;
    const size_t NN = (size_t)n;

    const int ra  = min(r0 + ln, n - 1);
    const int rbb = min(r0 + 16 + ln, n - 1);

    // gather x fragments once; reused by all 5 heads (replaces build_x + 5x re-read)
    short8 xf[2][8];
#pragma unroll
    for (int kk = 0; kk < 8; ++kk) {
        int c0 = kk * 32 + q * 8;
        xf[0][kk] = gather8(A, encS, ra, c0);
        xf[1][kk] = gather8(A, encS, rbb, c0);
    }

    floatx4 acc[8][2];
    floatx4 acc2[3][2];
    float mk0 = 0.f, mk1 = 0.f, mkb0 = 0.f, mkb1 = 0.f;

#pragma unroll 1
    for (int h = 0; h < 5; ++h) {
        const u16* W1g = A.W1t + h * 65536;
        const float* b1h = A.b1[h];
        const u16* w2th = A.W2t + ((h < 4) ? h * 16 : 64) * 256;

        layer1_part(xf, W1g, 0, q, ln, acc);
        if (h == 4) layer2_part<3>(acc, b1h, w2th, 0, q, ln, acc2);
        else        layer2_part<1>(acc, b1h, w2th, 0, q, ln, acc2);
        layer1_part(xf, W1g, 1, q, ln, acc);
        if (h == 4) layer2_part<3>(acc, b1h, w2th, 1, q, ln, acc2);
        else        layer2_part<1>(acc, b1h, w2th, 1, q, ln, acc2);

        // epilogue: acc2 lane(q,ln) reg r: n2 = mt*16 + q*4 + r, row = r0 + 16t + ln
        if (h == 0) {
            if (q == 0) {
                float bb = A.b2[0][0];
                int g0 = r0 + ln, g1 = r0 + 16 + ln;
                if (g0 < n) {
                    mk0 = 1.0f / (1.0f + expf(-(acc2[0][0][0] + bb)));
                    A.out[10 * NN + g0] = A.opa[g0];     // opacity passthrough
                }
                if (g1 < n) {
                    mk1 = 1.0f / (1.0f + expf(-(acc2[0][1][0] + bb)));
                    A.out[10 * NN + g1] = A.opa[g1];
                }
            }
            // broadcast mask to all q-groups of the wave (replaces LDS maskL)
            mkb0 = __shfl(mk0, ln, 64);
            mkb1 = __shfl(mk1, ln, 64);
        } else if (h < 4) {
            if (q == 0) {
                const float* b2h = A.b2[h];
#pragma unroll
                for (int t = 0; t < 2; ++t) {
                    int grow = r0 + 16 * t + ln;
                    float mk = t ? mkb1 : mkb0;
                    if (grow < n) {
                        if (h == 1) {
#pragma unroll
                            for (int r = 0; r < 3; ++r) {
                                float raw = acc2[0][t][r] + b2h[r];
                                A.out[59 * NN + (size_t)grow * 3 + r] = raw;
                                A.out[(size_t)grow * 3 + r] = A.pt[(size_t)grow * 3 + r] + raw * mk;
                            }
                        } else if (h == 2) {
#pragma unroll
                            for (int r = 0; r < 3; ++r) {
                                float raw = acc2[0][t][r] + b2h[r];
                                A.out[3 * NN + (size_t)grow * 3 + r] = A.scl[(size_t)grow * 3 + r] + raw * mk;
                            }
                        } else {
#pragma unroll
                            for (int r = 0; r < 4; ++r) {
                                float raw = acc2[0][t][r] + b2h[r];
                                A.out[6 * NN + (size_t)grow * 4 + r] = A.rot[(size_t)grow * 4 + r] + raw * mk;
                            }
                        }
                    }
                }
            }
        } else {
            const float* b2h = A.b2[4];
#pragma unroll
            for (int t = 0; t < 2; ++t) {
                int grow = r0 + 16 * t + ln;
                float mk = t ? mkb1 : mkb0;
                if (grow < n) {
#pragma unroll
                    for (int mt = 0; mt < 3; ++mt) {
                        int n2b = mt * 16 + q * 4;
                        floatx4 b2v = *(const floatx4*)(b2h + n2b);
                        floatx4 raw = acc2[mt][t] + b2v;
                        *(floatx4*)(A.out + 62 * NN + (size_t)grow * 48 + n2b) = raw;
                        floatx4 s = *(const floatx4*)(A.shs + (size_t)grow * 48 + n2b);
                        *(floatx4*)(A.out + 11 * NN + (size_t)grow * 48 + n2b) = s + raw * mk;
                    }
                }
            }
        }
    }
}

extern "C" void kernel_launch(void* const* d_in, const int* in_sizes, int n_in,
                              void* d_out, int out_size, void* d_ws, size_t ws_size,
                              hipStream_t stream)
{
    const float* opa  = (const float*)d_in[0];
    const float* shs  = (const float*)d_in[1];
    const float* te   = (const float*)d_in[2];
    const float* sem  = (const float*)d_in[3];
    const float* pt   = (const float*)d_in[4];
    const float* scl  = (const float*)d_in[5];
    const float* rot  = (const float*)d_in[6];
    const float* dx   = (const float*)d_in[7];

    WPtrs p;
    p.w1[0] = (const float*)d_in[8];  p.w2[0] = (const float*)d_in[10];
    p.w1[1] = (const float*)d_in[12]; p.w2[1] = (const float*)d_in[14];
    p.w1[2] = (const float*)d_in[16]; p.w2[2] = (const float*)d_in[18];
    p.w1[3] = (const float*)d_in[20]; p.w2[3] = (const float*)d_in[22];
    p.w1[4] = (const float*)d_in[24]; p.w2[4] = (const float*)d_in[26];

    const int n = in_sizes[0];               // 200000

    char* ws = (char*)d_ws;
    u16* W1t = (u16*)ws;                     // 5*65536 bf16 (swizzled)
    u16* W2t = W1t + 5 * 65536;              // 112*256 bf16
    u16* enc = W2t + 112 * 256;              // 64 bf16

    prep_weights<<<193, 256, 0, stream>>>(p, te, W1t, W2t, enc);

    FusedArgs A;
    A.W1t = W1t; A.W2t = W2t; A.enc = enc;
    A.b1[0] = (const float*)d_in[9];  A.b2[0] = (const float*)d_in[11];
    A.b1[1] = (const float*)d_in[13]; A.b2[1] = (const float*)d_in[15];
    A.b1[2] = (const float*)d_in[17]; A.b2[2] = (const float*)d_in[19];
    A.b1[3] = (const float*)d_in[21]; A.b2[3] = (const float*)d_in[23];
    A.b1[4] = (const float*)d_in[25]; A.b2[4] = (const float*)d_in[27];
    A.opa = opa; A.shs = shs; A.te = te; A.sem = sem;
    A.pt = pt; A.scl = scl; A.rot = rot; A.dxp = dx;
    A.out = (float*)d_out; A.n = n;

    int grid = (n + 127) / 128;              // 4 waves/block x 32 rows/wave
    fused_all<<<grid, 256, 0, stream>>>(A);
}

// Round 4
// 627.294 us; speedup vs baseline: 1.3910x; 1.3910x over previous
//
#include <hip/hip_runtime.h>
#include <math.h>

typedef unsigned short u16;
typedef __attribute__((ext_vector_type(8))) short short8;
typedef __attribute__((ext_vector_type(4))) float floatx4;

__device__ __forceinline__ u16 f2bf(float f) {
    union { float f; unsigned u; } v; v.f = f;
    unsigned r = v.u + 0x7fffu + ((v.u >> 16) & 1u);
    return (u16)(r >> 16);
}

struct WPtrs {
    const float* w1[5];
    const float* w2[5];
};

// ---------------- async global->LDS (16B per lane, wave-uniform LDS base) ----------------
typedef const __attribute__((address_space(1))) unsigned GUA;
typedef __attribute__((address_space(3))) unsigned LUA;

// stages 128 KiB (one head's swizzled W1) with 8 waves x 16 x 1KiB chunks
__device__ __forceinline__ void stage_w1(const u16* gbase, u16* lbase, int wave, int lane) {
    const char* g = (const char*)gbase;
    char* l = (char*)lbase;
#pragma unroll
    for (int i = 0; i < 16; ++i) {
        int off = (wave * 16 + i) * 1024;
        __builtin_amdgcn_global_load_lds((GUA*)(g + off + lane * 16), (LUA*)(l + off), 16, 0, 0);
    }
}

// ---------------- prep (unchanged layout) ----------------
// W1t: [head][n][k-chunks swizzled]: element (h,n,k) at h*65536 + n*256 + ((kc ^ (n&31))<<3) + (k&7)
// W2t: [112][256] rows: mask@0(16), pos@16, scl@32, rot@48, shs@64(48); W2t[roff+n2][k]=w2[k*od+n2]
// enc: 64 bf16 relu'd time positional encoding
__global__ void prep_weights(WPtrs p, const float* __restrict__ te,
                             u16* __restrict__ W1t, u16* __restrict__ W2t,
                             u16* __restrict__ enc)
{
    const int bid = blockIdx.x;
    const int tid = threadIdx.x;
    if (bid < 80) {
        __shared__ float tile[64 * 65];
        int h = bid / 16, t = bid % 16;
        int k0 = (t / 4) * 64, n0 = (t % 4) * 64;
        int nn = tid & 63, g = tid >> 6;
        const float* w1 = p.w1[h];
#pragma unroll
        for (int rep = 0; rep < 16; ++rep) {
            int kl = g * 16 + rep;
            int k = k0 + kl, nidx = n0 + nn;
            float v = (k < 255 && nidx < 255) ? w1[k * 255 + nidx] : 0.0f;
            tile[kl * 65 + nn] = v;
        }
        __syncthreads();
#pragma unroll
        for (int i = 0; i < 2; ++i) {
            int c = tid * 2 + i;            // 0..511
            int nl = c >> 3, kcl = c & 7;
            int n = n0 + nl;
            int kcg = (k0 >> 3) + kcl;
            short8 sv;
#pragma unroll
            for (int j = 0; j < 8; ++j)
                sv[j] = (short)f2bf(tile[(kcl * 8 + j) * 65 + nl]);
            *(short8*)(W1t + h * 65536 + n * 256 + (((kcg ^ (n & 31))) << 3)) = sv;
        }
    } else if (bid < 192) {
        int row = bid - 80;               // 0..111
        int h, roff, od;
        if (row < 16)      { h = 0; roff = 0;  od = 1; }
        else if (row < 32) { h = 1; roff = 16; od = 3; }
        else if (row < 48) { h = 2; roff = 32; od = 3; }
        else if (row < 64) { h = 3; roff = 48; od = 4; }
        else               { h = 4; roff = 64; od = 48; }
        int n2 = row - roff;
        int k = tid;
        float v = (k < 255 && n2 < od) ? p.w2[h][k * od + n2] : 0.0f;
        W2t[row * 256 + k] = f2bf(v);
    } else {
        if (tid < 64) {
            float t = te[0];
            float fi = (float)(tid & ~1);
            float freq = powf(10000.0f, fi * (1.0f / 32.0f));
            float a = t / freq;
            float v = (tid & 1) ? cosf(a) : sinf(a);
            enc[tid] = f2bf(fmaxf(v, 0.0f));
        }
    }
}

// ---------------- fused: x gathered to regs once, W1 LDS-staged per head ----------------
struct FusedArgs {
    const u16* W1t; const u16* W2t; const u16* enc;
    const float* b1[5]; const float* b2[5];
    const float* opa; const float* shs; const float* te; const float* sem;
    const float* pt;  const float* scl; const float* rot; const float* dxp;
    float* out; int n;
};

// build one 8-col chunk of x = relu(concat) for a row
__device__ __forceinline__ short8 gather8(const FusedArgs& A, int row, int c0)
{
    short8 sv;
    if (c0 >= 64 && c0 <= 176) {
        // pure semantic_feature fast path (cols within [59,187))
        const float* s = A.sem + (size_t)row * 128 + (c0 - 59);
        float4 a = *(const float4*)(s);
        float4 b = *(const float4*)(s + 4);
        sv[0] = (short)f2bf(fmaxf(a.x, 0.f)); sv[1] = (short)f2bf(fmaxf(a.y, 0.f));
        sv[2] = (short)f2bf(fmaxf(a.z, 0.f)); sv[3] = (short)f2bf(fmaxf(a.w, 0.f));
        sv[4] = (short)f2bf(fmaxf(b.x, 0.f)); sv[5] = (short)f2bf(fmaxf(b.y, 0.f));
        sv[6] = (short)f2bf(fmaxf(b.z, 0.f)); sv[7] = (short)f2bf(fmaxf(b.w, 0.f));
    } else if (c0 >= 192) {
        // pure time-positional-encoding chunk (already relu'd bf16 in global enc); c==255 pad 0
#pragma unroll
        for (int j = 0; j < 8; ++j) {
            int c = c0 + j;
            sv[j] = (c < 255) ? (short)A.enc[c - 191] : (short)0;
        }
    } else {
#pragma unroll
        for (int j = 0; j < 8; ++j) {
            int c = c0 + j;
            float v;
            if (c < 3)        v = A.pt[row * 3 + c];
            else if (c < 7)   v = A.rot[row * 4 + (c - 3)];
            else if (c < 10)  v = A.scl[row * 3 + (c - 7)];
            else if (c < 11)  v = A.opa[row];
            else if (c < 59)  v = A.shs[(size_t)row * 48 + (c - 11)];
            else if (c < 187) v = A.sem[(size_t)row * 128 + (c - 59)];
            else if (c < 190) v = A.dxp[row * 3 + (c - 187)];
            else if (c < 191) v = A.te[row];
            else { sv[j] = (short)A.enc[c - 191]; continue; }   // c==191 (enc[0], relu'd)
            sv[j] = (short)f2bf(fmaxf(v, 0.0f));
        }
    }
    return sv;
}

// layer1 half: h1 cols [part*128, part*128+128), W1 frags from LDS (swizzled layout).
// acc[ct][t] lane(q,ln) reg r: h1pre[c = part*128 + ct*16 + q*4 + r][row = r0 + 16t + ln]
__device__ __forceinline__ void layer1_part(const short8 (&xf)[2][8], const u16* W1L,
                                            int part, int q, int ln, floatx4 (&acc)[8][2])
{
#pragma unroll
    for (int ct = 0; ct < 8; ++ct) {
        acc[ct][0] = (floatx4){0.f, 0.f, 0.f, 0.f};
        acc[ct][1] = (floatx4){0.f, 0.f, 0.f, 0.f};
    }
#pragma unroll
    for (int kk = 0; kk < 8; ++kk) {
#pragma unroll
        for (int ct = 0; ct < 8; ++ct) {
            int nidx = part * 128 + ct * 16 + ln;
            int sw = (kk * 4 + q) ^ (nidx & 31);
            short8 wf = *(const short8*)(W1L + nidx * 256 + (sw << 3));
            acc[ct][0] = __builtin_amdgcn_mfma_f32_16x16x32_bf16(wf, xf[0][kk], acc[ct][0], 0, 0, 0);
            acc[ct][1] = __builtin_amdgcn_mfma_f32_16x16x32_bf16(wf, xf[1][kk], acc[ct][1], 0, 0, 0);
        }
    }
}

// layer2 half: bias+relu acc in place, then accumulate acc2 over this half's 128 k (ks 0..3).
template<int MT>
__device__ __forceinline__ void layer2_part(floatx4 (&acc)[8][2], const float* __restrict__ b1h,
                                            const u16* __restrict__ w2th, int part, int q, int ln,
                                            floatx4 (&acc2)[3][2])
{
#pragma unroll
    for (int ct = 0; ct < 8; ++ct) {
        // b1 has exactly 255 floats; the (part==1, ct==7, q==3) quad would read b1[255] OOB.
        floatx4 b4;
        if (part == 1 && ct == 7) {
            if (q == 3) {
                b4.x = b1h[252]; b4.y = b1h[253]; b4.z = b1h[254]; b4.w = 0.f;
            } else {
                b4 = *(const floatx4*)(b1h + 240 + q * 4);
            }
        } else {
            b4 = *(const floatx4*)(b1h + part * 128 + ct * 16 + q * 4);
        }
#pragma unroll
        for (int t = 0; t < 2; ++t) {
            floatx4 v = acc[ct][t];
            v.x = fmaxf(v.x + b4.x, 0.f);
            v.y = fmaxf(v.y + b4.y, 0.f);
            v.z = fmaxf(v.z + b4.z, 0.f);
            v.w = fmaxf(v.w + b4.w, 0.f);
            acc[ct][t] = v;
        }
    }
    if (part == 0) {
#pragma unroll
        for (int mt = 0; mt < MT; ++mt) {
            acc2[mt][0] = (floatx4){0.f, 0.f, 0.f, 0.f};
            acc2[mt][1] = (floatx4){0.f, 0.f, 0.f, 0.f};
        }
    }
#pragma unroll
    for (int ks = 0; ks < 4; ++ks) {
        int ksg = part * 4 + ks;
        short8 a2[MT];
#pragma unroll
        for (int mt = 0; mt < MT; ++mt)
            a2[mt] = *(const short8*)(w2th + (mt * 16 + ln) * 256 + ksg * 32 + q * 8);
#pragma unroll
        for (int t = 0; t < 2; ++t) {
            short8 bfrag;
#pragma unroll
            for (int j = 0; j < 8; ++j) {
                int idx = (((q * 2 + (j >> 2)) & 3) << 4) | ln;
                float v0 = __shfl(acc[ks * 2 + 0][t][j & 3], idx, 64);
                float v1 = __shfl(acc[ks * 2 + 1][t][j & 3], idx, 64);
                float v = (q >> 1) ? v1 : v0;
                bfrag[j] = (short)f2bf(v);
            }
#pragma unroll
            for (int mt = 0; mt < MT; ++mt)
                acc2[mt][t] = __builtin_amdgcn_mfma_f32_16x16x32_bf16(a2[mt], bfrag, acc2[mt][t], 0, 0, 0);
        }
    }
}

__global__ __launch_bounds__(512, 2) void fused_all(FusedArgs A)
{
    extern __shared__ char smem[];
    u16* W1L = (u16*)smem;                  // 131072 B: current head's swizzled W1

    const int tid = threadIdx.x;
    const int wave = tid >> 6;
    const int lane = tid & 63;
    const int q = lane >> 4, ln = lane & 15;
    const int n = A.n;
    const size_t NN = (size_t)n;

    stage_w1(A.W1t, W1L, wave, lane);       // head 0 DMA in flight during gather

    // each wave permanently owns one 32-row tile; block covers 256 rows
    const int r0 = blockIdx.x * 256 + wave * 32;
    const int ra  = min(r0 + ln, n - 1);
    const int rbb = min(r0 + 16 + ln, n - 1);

    // gather x fragments once; reused by all 5 heads
    short8 xf[2][8];
#pragma unroll
    for (int kk = 0; kk < 8; ++kk) {
        int c0 = kk * 32 + q * 8;
        xf[0][kk] = gather8(A, ra, c0);
        xf[1][kk] = gather8(A, rbb, c0);
    }

    floatx4 acc[8][2];
    floatx4 acc2[3][2];
    float mk0 = 0.f, mk1 = 0.f, mkb0 = 0.f, mkb1 = 0.f;

    __syncthreads();   // head-0 W1 staged (barrier drains vmcnt) + block synced

#pragma unroll 1
    for (int h = 0; h < 5; ++h) {
        const float* b1h = A.b1[h];
        const u16* w2th = A.W2t + ((h < 4) ? h * 16 : 64) * 256;

        layer1_part(xf, W1L, 0, q, ln, acc);
        if (h == 4) layer2_part<3>(acc, b1h, w2th, 0, q, ln, acc2);
        else        layer2_part<1>(acc, b1h, w2th, 0, q, ln, acc2);
        layer1_part(xf, W1L, 1, q, ln, acc);

        __syncthreads();                    // all waves done reading W1L for head h
        if (h < 4) stage_w1(A.W1t + (h + 1) * 65536, W1L, wave, lane);  // prefetch next head

        if (h == 4) layer2_part<3>(acc, b1h, w2th, 1, q, ln, acc2);
        else        layer2_part<1>(acc, b1h, w2th, 1, q, ln, acc2);

        // epilogue: acc2 lane(q,ln) reg r: n2 = mt*16 + q*4 + r, row = r0 + 16t + ln
        if (h == 0) {
            if (q == 0) {
                float bb = A.b2[0][0];
                int g0 = r0 + ln, g1 = r0 + 16 + ln;
                if (g0 < n) {
                    mk0 = 1.0f / (1.0f + expf(-(acc2[0][0][0] + bb)));
                    A.out[10 * NN + g0] = A.opa[g0];     // opacity passthrough
                }
                if (g1 < n) {
                    mk1 = 1.0f / (1.0f + expf(-(acc2[0][1][0] + bb)));
                    A.out[10 * NN + g1] = A.opa[g1];
                }
            }
            // broadcast mask to all q-groups of the wave
            mkb0 = __shfl(mk0, ln, 64);
            mkb1 = __shfl(mk1, ln, 64);
        } else if (h < 4) {
            if (q == 0) {
                const float* b2h = A.b2[h];
#pragma unroll
                for (int t = 0; t < 2; ++t) {
                    int grow = r0 + 16 * t + ln;
                    float mk = t ? mkb1 : mkb0;
                    if (grow < n) {
                        if (h == 1) {
#pragma unroll
                            for (int r = 0; r < 3; ++r) {
                                float raw = acc2[0][t][r] + b2h[r];
                                A.out[59 * NN + (size_t)grow * 3 + r] = raw;
                                A.out[(size_t)grow * 3 + r] = A.pt[(size_t)grow * 3 + r] + raw * mk;
                            }
                        } else if (h == 2) {
#pragma unroll
                            for (int r = 0; r < 3; ++r) {
                                float raw = acc2[0][t][r] + b2h[r];
                                A.out[3 * NN + (size_t)grow * 3 + r] = A.scl[(size_t)grow * 3 + r] + raw * mk;
                            }
                        } else {
#pragma unroll
                            for (int r = 0; r < 4; ++r) {
                                float raw = acc2[0][t][r] + b2h[r];
                                A.out[6 * NN + (size_t)grow * 4 + r] = A.rot[(size_t)grow * 4 + r] + raw * mk;
                            }
                        }
                    }
                }
            }
        } else {
            const float* b2h = A.b2[4];
#pragma unroll
            for (int t = 0; t < 2; ++t) {
                int grow = r0 + 16 * t + ln;
                float mk = t ? mkb1 : mkb0;
                if (grow < n) {
#pragma unroll
                    for (int mt = 0; mt < 3; ++mt) {
                        int n2b = mt * 16 + q * 4;
                        floatx4 b2v = *(const floatx4*)(b2h + n2b);
                        floatx4 raw = acc2[mt][t] + b2v;
                        *(floatx4*)(A.out + 62 * NN + (size_t)grow * 48 + n2b) = raw;
                        floatx4 s = *(const floatx4*)(A.shs + (size_t)grow * 48 + n2b);
                        *(floatx4*)(A.out + 11 * NN + (size_t)grow * 48 + n2b) = s + raw * mk;
                    }
                }
            }
        }

        if (h < 4) __syncthreads();         // prefetch DMA drained before next head's reads
    }
}

extern "C" void kernel_launch(void* const* d_in, const int* in_sizes, int n_in,
                              void* d_out, int out_size, void* d_ws, size_t ws_size,
                              hipStream_t stream)
{
    const float* opa  = (const float*)d_in[0];
    const float* shs  = (const float*)d_in[1];
    const float* te   = (const float*)d_in[2];
    const float* sem  = (const float*)d_in[3];
    const float* pt   = (const float*)d_in[4];
    const float* scl  = (const float*)d_in[5];
    const float* rot  = (const float*)d_in[6];
    const float* dx   = (const float*)d_in[7];

    WPtrs p;
    p.w1[0] = (const float*)d_in[8];  p.w2[0] = (const float*)d_in[10];
    p.w1[1] = (const float*)d_in[12]; p.w2[1] = (const float*)d_in[14];
    p.w1[2] = (const float*)d_in[16]; p.w2[2] = (const float*)d_in[18];
    p.w1[3] = (const float*)d_in[20]; p.w2[3] = (const float*)d_in[22];
    p.w1[4] = (const float*)d_in[24]; p.w2[4] = (const float*)d_in[26];

    const int n = in_sizes[0];               // 200000

    char* ws = (char*)d_ws;
    u16* W1t = (u16*)ws;                     // 5*65536 bf16 (swizzled)
    u16* W2t = W1t + 5 * 65536;              // 112*256 bf16
    u16* enc = W2t + 112 * 256;              // 64 bf16

    prep_weights<<<193, 256, 0, stream>>>(p, te, W1t, W2t, enc);

    FusedArgs A;
    A.W1t = W1t; A.W2t = W2t; A.enc = enc;
    A.b1[0] = (const float*)d_in[9];  A.b2[0] = (const float*)d_in[11];
    A.b1[1] = (const float*)d_in[13]; A.b2[1] = (const float*)d_in[15];
    A.b1[2] = (const float*)d_in[17]; A.b2[2] = (const float*)d_in[19];
    A.b1[3] = (const float*)d_in[21]; A.b2[3] = (const float*)d_in[23];
    A.b1[4] = (const float*)d_in[25]; A.b2[4] = (const float*)d_in[27];
    A.opa = opa; A.shs = shs; A.te = te; A.sem = sem;
    A.pt = pt; A.scl = scl; A.rot = rot; A.dxp = dx;
    A.out = (float*)d_out; A.n = n;

    int grid = (n + 255) / 256;              // 782 blocks x 8 waves x 32 rows
    fused_all<<<grid, 512, 131072, stream>>>(A);
}

// Round 6
// 600.211 us; speedup vs baseline: 1.4537x; 1.0451x over previous
//
#include <hip/hip_runtime.h>
#include <math.h>

typedef unsigned short u16;
typedef __attribute__((ext_vector_type(8))) short short8;
typedef __attribute__((ext_vector_type(4))) float floatx4;

__device__ __forceinline__ u16 f2bf(float f) {
    union { float f; unsigned u; } v; v.f = f;
    unsigned r = v.u + 0x7fffu + ((v.u >> 16) & 1u);
    return (u16)(r >> 16);
}

struct WPtrs {
    const float* w1[5];
    const float* w2[5];
};

// ---------------- async global->LDS (16B per lane, wave-uniform LDS base) ----------------
typedef const __attribute__((address_space(1))) unsigned GUA;
typedef __attribute__((address_space(3))) unsigned LUA;

// stage one 32 KiB chunk with 8 waves x 4 x 1 KiB
__device__ __forceinline__ void stage32(const u16* gbase, u16* lbase, int wave, int lane) {
    const char* g = (const char*)gbase;
    char* l = (char*)lbase;
#pragma unroll
    for (int i = 0; i < 4; ++i) {
        int off = (wave * 4 + i) * 1024;
        __builtin_amdgcn_global_load_lds((GUA*)(g + off + lane * 16), (LUA*)(l + off), 16, 0, 0);
    }
}

// ---------------- prep ----------------
// W1t: [head][n][k-chunks swizzled]: element (h,n,k) at h*65536 + n*256 + ((kc ^ (n&31))<<3) + (k&7)
// W2t: [112][256] bf16 rows (only rows 64..111 = shs head used by fused now)
// W2f: [11][256] f32 transposed small-head weights: rows 0:mask, 1-3:pos, 4-6:scl, 7-10:rot
// enc: 64 bf16 relu'd time positional encoding
__global__ void prep_weights(WPtrs p, const float* __restrict__ te,
                             u16* __restrict__ W1t, u16* __restrict__ W2t,
                             float* __restrict__ W2f, u16* __restrict__ enc)
{
    const int bid = blockIdx.x;
    const int tid = threadIdx.x;
    if (bid < 80) {
        __shared__ float tile[64 * 65];
        int h = bid / 16, t = bid % 16;
        int k0 = (t / 4) * 64, n0 = (t % 4) * 64;
        int nn = tid & 63, g = tid >> 6;
        const float* w1 = p.w1[h];
#pragma unroll
        for (int rep = 0; rep < 16; ++rep) {
            int kl = g * 16 + rep;
            int k = k0 + kl, nidx = n0 + nn;
            float v = (k < 255 && nidx < 255) ? w1[k * 255 + nidx] : 0.0f;
            tile[kl * 65 + nn] = v;
        }
        __syncthreads();
#pragma unroll
        for (int i = 0; i < 2; ++i) {
            int c = tid * 2 + i;            // 0..511
            int nl = c >> 3, kcl = c & 7;
            int n = n0 + nl;
            int kcg = (k0 >> 3) + kcl;
            short8 sv;
#pragma unroll
            for (int j = 0; j < 8; ++j)
                sv[j] = (short)f2bf(tile[(kcl * 8 + j) * 65 + nl]);
            *(short8*)(W1t + h * 65536 + n * 256 + (((kcg ^ (n & 31))) << 3)) = sv;
        }
    } else if (bid < 192) {
        int row = bid - 80;               // 0..111
        int h, roff, od;
        if (row < 16)      { h = 0; roff = 0;  od = 1; }
        else if (row < 32) { h = 1; roff = 16; od = 3; }
        else if (row < 48) { h = 2; roff = 32; od = 3; }
        else if (row < 64) { h = 3; roff = 48; od = 4; }
        else               { h = 4; roff = 64; od = 48; }
        int n2 = row - roff;
        int k = tid;
        float v = (k < 255 && n2 < od) ? p.w2[h][k * od + n2] : 0.0f;
        W2t[row * 256 + k] = f2bf(v);
        if (h < 4 && n2 < od) {
            int r11b = (h == 0) ? 0 : (h == 1) ? 1 : (h == 2) ? 4 : 7;
            W2f[(r11b + n2) * 256 + k] = v;   // f32 transposed copy for VALU layer2
        }
    } else {
        if (tid < 64) {
            float t = te[0];
            float fi = (float)(tid & ~1);
            float freq = powf(10000.0f, fi * (1.0f / 32.0f));
            float a = t / freq;
            float v = (tid & 1) ? cosf(a) : sinf(a);
            enc[tid] = f2bf(fmaxf(v, 0.0f));
        }
    }
}

// ---------------- fused: 16 rows/wave, quarter-staged W1, VALU small-head layer2 ----------------
struct FusedArgs {
    const u16* W1t; const u16* W2t; const float* W2f; const u16* enc;
    const float* b1[5]; const float* b2[5];
    const float* opa; const float* shs; const float* te; const float* sem;
    const float* pt;  const float* scl; const float* rot; const float* dxp;
    float* out; int n;
};

// build one 8-col chunk of x = relu(concat) for a row
__device__ __forceinline__ short8 gather8(const FusedArgs& A, int row, int c0)
{
    short8 sv;
    if (c0 >= 64 && c0 <= 176) {
        const float* s = A.sem + (size_t)row * 128 + (c0 - 59);
        float4 a = *(const float4*)(s);
        float4 b = *(const float4*)(s + 4);
        sv[0] = (short)f2bf(fmaxf(a.x, 0.f)); sv[1] = (short)f2bf(fmaxf(a.y, 0.f));
        sv[2] = (short)f2bf(fmaxf(a.z, 0.f)); sv[3] = (short)f2bf(fmaxf(a.w, 0.f));
        sv[4] = (short)f2bf(fmaxf(b.x, 0.f)); sv[5] = (short)f2bf(fmaxf(b.y, 0.f));
        sv[6] = (short)f2bf(fmaxf(b.z, 0.f)); sv[7] = (short)f2bf(fmaxf(b.w, 0.f));
    } else if (c0 >= 192) {
#pragma unroll
        for (int j = 0; j < 8; ++j) {
            int c = c0 + j;
            sv[j] = (c < 255) ? (short)A.enc[c - 191] : (short)0;
        }
    } else {
#pragma unroll
        for (int j = 0; j < 8; ++j) {
            int c = c0 + j;
            float v;
            if (c < 3)        v = A.pt[row * 3 + c];
            else if (c < 7)   v = A.rot[row * 4 + (c - 3)];
            else if (c < 10)  v = A.scl[row * 3 + (c - 7)];
            else if (c < 11)  v = A.opa[row];
            else if (c < 59)  v = A.shs[(size_t)row * 48 + (c - 11)];
            else if (c < 187) v = A.sem[(size_t)row * 128 + (c - 59)];
            else if (c < 190) v = A.dxp[row * 3 + (c - 187)];
            else if (c < 191) v = A.te[row];
            else { sv[j] = (short)A.enc[c - 191]; continue; }   // c==191 (enc[0], relu'd)
            sv[j] = (short)f2bf(fmaxf(v, 0.0f));
        }
    }
    return sv;
}

__global__ __launch_bounds__(512, 4) void fused_all(FusedArgs A)
{
    __shared__ u16 W1L[2][16384];           // 2 x 32 KiB double buffer

    const int tid = threadIdx.x;
    const int wave = tid >> 6;
    const int lane = tid & 63;
    const int q = lane >> 4, ln = lane & 15;
    const int n = A.n;
    const size_t NN = (size_t)n;

    stage32(A.W1t, W1L[0], wave, lane);     // chunk 0 DMA in flight during gather

    // each wave owns one 16-row tile; block covers 128 rows
    const int r0 = blockIdx.x * 128 + wave * 16;
    const int ra = min(r0 + ln, n - 1);
    const int grow = r0 + ln;

    // gather x fragments once; reused by all 5 heads
    short8 xf[8];
#pragma unroll
    for (int kk = 0; kk < 8; ++kk)
        xf[kk] = gather8(A, ra, kk * 32 + q * 8);

    __syncthreads();                        // chunk-0 staged (barrier drains vmcnt)

    floatx4 acc[4];
    floatx4 acc2[3];
    float out2[4];
    float mkb = 0.f;

#pragma unroll 1
    for (int c = 0; c < 20; ++c) {
        const int h = c >> 2;               // head
        const int Q = c & 3;                // quarter (h1 cols [Q*64, Q*64+64))
        if (c + 1 < 20)
            stage32(A.W1t + (size_t)(c + 1) * 16384, W1L[(c + 1) & 1], wave, lane);
        const u16* buf = W1L[c & 1];

        // ---- layer1 quarter: 64 h1 cols, all 256 k ----
#pragma unroll
        for (int ct = 0; ct < 4; ++ct) acc[ct] = (floatx4){0.f, 0.f, 0.f, 0.f};
#pragma unroll
        for (int kk = 0; kk < 8; ++kk) {
#pragma unroll
            for (int ct = 0; ct < 4; ++ct) {
                int nl = ct * 16 + ln;
                int sw = (kk * 4 + q) ^ (nl & 31);
                short8 wf = *(const short8*)(buf + nl * 256 + (sw << 3));
                acc[ct] = __builtin_amdgcn_mfma_f32_16x16x32_bf16(wf, xf[kk], acc[ct], 0, 0, 0);
            }
        }

        // ---- bias + relu (lane q,ln reg r holds h1[Q*64 + ct*16 + q*4 + r][row r0+ln]) ----
        const float* b1h = A.b1[h];
#pragma unroll
        for (int ct = 0; ct < 4; ++ct) {
            floatx4 b4;
            if (Q == 3 && ct == 3) {        // b1 has 255 floats; col 255 is zero pad
                if (q == 3) { b4.x = b1h[252]; b4.y = b1h[253]; b4.z = b1h[254]; b4.w = 0.f; }
                else        b4 = *(const floatx4*)(b1h + 240 + q * 4);
            } else {
                b4 = *(const floatx4*)(b1h + Q * 64 + ct * 16 + q * 4);
            }
            floatx4 v = acc[ct];
            v.x = fmaxf(v.x + b4.x, 0.f);
            v.y = fmaxf(v.y + b4.y, 0.f);
            v.z = fmaxf(v.z + b4.z, 0.f);
            v.w = fmaxf(v.w + b4.w, 0.f);
            acc[ct] = v;
        }

        if (h < 4) {
            // ---- small-head layer2 quarter: f32 dot-products, no MFMA/shuffle ----
            const int od = (h == 0) ? 1 : (h == 3) ? 4 : 3;
            const int r11b = (h == 0) ? 0 : (h == 1) ? 1 : (h == 2) ? 4 : 7;
            if (Q == 0) {
#pragma unroll
                for (int m = 0; m < 4; ++m) out2[m] = 0.f;
            }
            const float* wb = A.W2f + r11b * 256 + Q * 64 + q * 4;
#pragma unroll
            for (int n2 = 0; n2 < 4; ++n2) {
                if (n2 < od) {
#pragma unroll
                    for (int ct = 0; ct < 4; ++ct) {
                        floatx4 w4 = *(const floatx4*)(wb + n2 * 256 + ct * 16);
                        out2[n2] = fmaf(acc[ct].x, w4.x, out2[n2]);
                        out2[n2] = fmaf(acc[ct].y, w4.y, out2[n2]);
                        out2[n2] = fmaf(acc[ct].z, w4.z, out2[n2]);
                        out2[n2] = fmaf(acc[ct].w, w4.w, out2[n2]);
                    }
                }
            }
            if (Q == 3) {
                // reduce across q-groups; then every lane holds the full sums for its row
#pragma unroll
                for (int n2 = 0; n2 < 4; ++n2) {
                    float v = out2[n2];
                    v += __shfl_xor(v, 16, 64);
                    v += __shfl_xor(v, 32, 64);
                    out2[n2] = v;
                }
                const float* b2h = A.b2[h];
                if (h == 0) {
                    mkb = 1.0f / (1.0f + expf(-(out2[0] + b2h[0])));
                    if (q == 0 && grow < n) A.out[10 * NN + grow] = A.opa[grow];
                } else if (grow < n && q == 0) {
                    if (h == 1) {
#pragma unroll
                        for (int r = 0; r < 3; ++r) {
                            float raw = out2[r] + b2h[r];
                            A.out[59 * NN + (size_t)grow * 3 + r] = raw;
                            A.out[(size_t)grow * 3 + r] = A.pt[(size_t)grow * 3 + r] + raw * mkb;
                        }
                    } else if (h == 2) {
#pragma unroll
                        for (int r = 0; r < 3; ++r) {
                            float raw = out2[r] + b2h[r];
                            A.out[3 * NN + (size_t)grow * 3 + r] = A.scl[(size_t)grow * 3 + r] + raw * mkb;
                        }
                    } else {
#pragma unroll
                        for (int r = 0; r < 4; ++r) {
                            float raw = out2[r] + b2h[r];
                            A.out[6 * NN + (size_t)grow * 4 + r] = A.rot[(size_t)grow * 4 + r] + raw * mkb;
                        }
                    }
                }
            }
        } else {
            // ---- shs head layer2 quarter: MFMA with shuffled B-fragment ----
            if (Q == 0) {
#pragma unroll
                for (int mt = 0; mt < 3; ++mt) acc2[mt] = (floatx4){0.f, 0.f, 0.f, 0.f};
            }
            const u16* w2th = A.W2t + 64 * 256;
#pragma unroll
            for (int ks = 0; ks < 2; ++ks) {
                int ksg = Q * 2 + ks;
                short8 a2[3];
#pragma unroll
                for (int mt = 0; mt < 3; ++mt)
                    a2[mt] = *(const short8*)(w2th + (mt * 16 + ln) * 256 + ksg * 32 + q * 8);
                short8 bfrag;
#pragma unroll
                for (int j = 0; j < 8; ++j) {
                    int idx = (((q * 2 + (j >> 2)) & 3) << 4) | ln;
                    float v0 = __shfl(acc[ks * 2 + 0][j & 3], idx, 64);
                    float v1 = __shfl(acc[ks * 2 + 1][j & 3], idx, 64);
                    bfrag[j] = (short)f2bf((q >> 1) ? v1 : v0);
                }
#pragma unroll
                for (int mt = 0; mt < 3; ++mt)
                    acc2[mt] = __builtin_amdgcn_mfma_f32_16x16x32_bf16(a2[mt], bfrag, acc2[mt], 0, 0, 0);
            }
            if (Q == 3 && grow < n) {
                const float* b2h = A.b2[4];
#pragma unroll
                for (int mt = 0; mt < 3; ++mt) {
                    int n2b = mt * 16 + q * 4;
                    floatx4 b2v = *(const floatx4*)(b2h + n2b);
                    floatx4 raw = acc2[mt] + b2v;
                    *(floatx4*)(A.out + 62 * NN + (size_t)grow * 48 + n2b) = raw;
                    floatx4 s = *(const floatx4*)(A.shs + (size_t)grow * 48 + n2b);
                    *(floatx4*)(A.out + 11 * NN + (size_t)grow * 48 + n2b) = s + raw * mkb;
                }
            }
        }

        __syncthreads();   // drains next-chunk DMA; all waves done with buf[c&1]
    }
}

extern "C" void kernel_launch(void* const* d_in, const int* in_sizes, int n_in,
                              void* d_out, int out_size, void* d_ws, size_t ws_size,
                              hipStream_t stream)
{
    const float* opa  = (const float*)d_in[0];
    const float* shs  = (const float*)d_in[1];
    const float* te   = (const float*)d_in[2];
    const float* sem  = (const float*)d_in[3];
    const float* pt   = (const float*)d_in[4];
    const float* scl  = (const float*)d_in[5];
    const float* rot  = (const float*)d_in[6];
    const float* dx   = (const float*)d_in[7];

    WPtrs p;
    p.w1[0] = (const float*)d_in[8];  p.w2[0] = (const float*)d_in[10];
    p.w1[1] = (const float*)d_in[12]; p.w2[1] = (const float*)d_in[14];
    p.w1[2] = (const float*)d_in[16]; p.w2[2] = (const float*)d_in[18];
    p.w1[3] = (const float*)d_in[20]; p.w2[3] = (const float*)d_in[22];
    p.w1[4] = (const float*)d_in[24]; p.w2[4] = (const float*)d_in[26];

    const int n = in_sizes[0];               // 200000

    char* ws = (char*)d_ws;
    u16*   W1t = (u16*)ws;                       // 5*65536 bf16 (swizzled), 655360 B
    u16*   W2t = W1t + 5 * 65536;                // 112*256 bf16, 57344 B
    float* W2f = (float*)(ws + 655360 + 57344);  // 11*256 f32, 11264 B (16B aligned)
    u16*   enc = (u16*)(ws + 655360 + 57344 + 11264); // 64 bf16

    prep_weights<<<193, 256, 0, stream>>>(p, te, W1t, W2t, W2f, enc);

    FusedArgs A;
    A.W1t = W1t; A.W2t = W2t; A.W2f = W2f; A.enc = enc;
    A.b1[0] = (const float*)d_in[9];  A.b2[0] = (const float*)d_in[11];
    A.b1[1] = (const float*)d_in[13]; A.b2[1] = (const float*)d_in[15];
    A.b1[2] = (const float*)d_in[17]; A.b2[2] = (const float*)d_in[19];
    A.b1[3] = (const float*)d_in[21]; A.b2[3] = (const float*)d_in[23];
    A.b1[4] = (const float*)d_in[25]; A.b2[4] = (const float*)d_in[27];
    A.opa = opa; A.shs = shs; A.te = te; A.sem = sem;
    A.pt = pt; A.scl = scl; A.rot = rot; A.dxp = dx;
    A.out = (float*)d_out; A.n = n;

    int grid = (n + 127) / 128;              // 1563 blocks x 8 waves x 16 rows
    fused_all<<<grid, 512, 0, stream>>>(A);
}

// Round 7
// 534.444 us; speedup vs baseline: 1.6326x; 1.1231x over previous
//
#include <hip/hip_runtime.h>
#include <math.h>

typedef unsigned short u16;
typedef __attribute__((ext_vector_type(8))) short short8;
typedef __attribute__((ext_vector_type(4))) float floatx4;

__device__ __forceinline__ u16 f2bf(float f) {
    union { float f; unsigned u; } v; v.f = f;
    unsigned r = v.u + 0x7fffu + ((v.u >> 16) & 1u);
    return (u16)(r >> 16);
}

struct WPtrs {
    const float* w1[5];
    const float* w2[5];
    const float* b1[5];
};

// ---------------- async global->LDS (16B per lane, wave-uniform LDS base) ----------------
typedef const __attribute__((address_space(1))) unsigned GUA;
typedef __attribute__((address_space(3))) unsigned LUA;

// stage one 24 KiB chunk with 4 waves x 6 x 1 KiB
__device__ __forceinline__ void stage24(const u16* gbase, u16* lbase, int wave, int lane) {
    const char* g = (const char*)gbase;
    char* l = (char*)lbase;
#pragma unroll
    for (int i = 0; i < 6; ++i) {
        int off = (wave * 6 + i) * 1024;
        __builtin_amdgcn_global_load_lds((GUA*)(g + off + lane * 16), (LUA*)(l + off), 16, 0, 0);
    }
}

// ---------------- prep ----------------
// W1t: [head][n=256][k=192 in swizzled 8-chunks]: (h,n,k) at h*49152 + n*192 + ((kc ^ (n&7))<<3) + (k&7)
//      k 0..190 real (x cols 0..190), k=191 zero pad. tpe cols (191..254) folded into b1eff.
// W2t: [112][256] bf16 rows (only rows 64..111 = shs head used in fused)
// W2f: [11][256] f32 transposed small-head weights: 0:mask, 1-3:pos, 4-6:scl, 7-10:rot
// b1eff: [5][256] f32: b1[col] + sum_j W1[191+j][col]*relu(enc[j]); entry 255 = 0
__global__ void prep_weights(WPtrs p, const float* __restrict__ te,
                             u16* __restrict__ W1t, u16* __restrict__ W2t,
                             float* __restrict__ W2f, float* __restrict__ b1eff)
{
    const int bid = blockIdx.x;
    const int tid = threadIdx.x;
    if (bid < 60) {
        // W1 64x64 tile transpose + swizzle (12 tiles/head: k0 in {0,64,128})
        __shared__ float tile[64 * 65];
        int h = bid / 12, t = bid % 12;
        int k0 = (t / 4) * 64, n0 = (t % 4) * 64;
        int nn = tid & 63, g = tid >> 6;
        const float* w1 = p.w1[h];
#pragma unroll
        for (int rep = 0; rep < 16; ++rep) {
            int kl = g * 16 + rep;
            int k = k0 + kl, nidx = n0 + nn;
            float v = (k < 191 && nidx < 255) ? w1[k * 255 + nidx] : 0.0f;
            tile[kl * 65 + nn] = v;
        }
        __syncthreads();
#pragma unroll
        for (int i = 0; i < 2; ++i) {
            int c = tid * 2 + i;            // 0..511
            int nl = c >> 3, kcl = c & 7;
            int n = n0 + nl;
            int kcg = (k0 >> 3) + kcl;      // 0..23
            short8 sv;
#pragma unroll
            for (int j = 0; j < 8; ++j)
                sv[j] = (short)f2bf(tile[(kcl * 8 + j) * 65 + nl]);
            *(short8*)(W1t + h * 49152 + n * 192 + ((kcg ^ (n & 7)) << 3)) = sv;
        }
    } else if (bid < 172) {
        int row = bid - 60;               // 0..111
        int h, roff, od;
        if (row < 16)      { h = 0; roff = 0;  od = 1; }
        else if (row < 32) { h = 1; roff = 16; od = 3; }
        else if (row < 48) { h = 2; roff = 32; od = 3; }
        else if (row < 64) { h = 3; roff = 48; od = 4; }
        else               { h = 4; roff = 64; od = 48; }
        int n2 = row - roff;
        int k = tid;
        float v = (k < 255 && n2 < od) ? p.w2[h][k * od + n2] : 0.0f;
        W2t[row * 256 + k] = f2bf(v);
        if (h < 4 && n2 < od) {
            int r11b = (h == 0) ? 0 : (h == 1) ? 1 : (h == 2) ? 4 : 7;
            W2f[(r11b + n2) * 256 + k] = v;   // f32 transposed copy for VALU layer2
        }
    } else {
        // b1eff: fold relu'd time positional encoding into the layer-1 bias
        __shared__ float encL[64];
        if (tid < 64) {
            float t = te[0];
            float fi = (float)(tid & ~1);
            float freq = powf(10000.0f, fi * (1.0f / 32.0f));
            float a = t / freq;
            float v = (tid & 1) ? cosf(a) : sinf(a);
            encL[tid] = fmaxf(v, 0.0f);
        }
        __syncthreads();
        for (int e = tid; e < 5 * 256; e += 256) {
            int h = e >> 8, col = e & 255;
            float s = 0.0f;
            if (col < 255) {
                s = p.b1[h][col];
                const float* w1 = p.w1[h];
#pragma unroll 8
                for (int j = 0; j < 64; ++j)
                    s += w1[(191 + j) * 255 + col] * encL[j];
            }
            b1eff[h * 256 + col] = s;
        }
    }
}

// ---------------- fused: 32 rows/wave, 24 KB quarter-chunks, k=192 ----------------
struct FusedArgs {
    const u16* W1t; const u16* W2t; const float* W2f; const float* b1eff;
    const float* b2[5];
    const float* opa; const float* shs; const float* te; const float* sem;
    const float* pt;  const float* scl; const float* rot; const float* dxp;
    float* out; int n;
};

// build one 8-col chunk of x = relu(concat) for a row; cols 0..190 real, col 191 = 0 pad
__device__ __forceinline__ short8 gather8(const FusedArgs& A, int row, int c0)
{
    short8 sv;
    if (c0 >= 64 && c0 <= 176) {
        const float* s = A.sem + (size_t)row * 128 + (c0 - 59);
        float4 a = *(const float4*)(s);
        float4 b = *(const float4*)(s + 4);
        sv[0] = (short)f2bf(fmaxf(a.x, 0.f)); sv[1] = (short)f2bf(fmaxf(a.y, 0.f));
        sv[2] = (short)f2bf(fmaxf(a.z, 0.f)); sv[3] = (short)f2bf(fmaxf(a.w, 0.f));
        sv[4] = (short)f2bf(fmaxf(b.x, 0.f)); sv[5] = (short)f2bf(fmaxf(b.y, 0.f));
        sv[6] = (short)f2bf(fmaxf(b.z, 0.f)); sv[7] = (short)f2bf(fmaxf(b.w, 0.f));
    } else {
#pragma unroll
        for (int j = 0; j < 8; ++j) {
            int c = c0 + j;
            float v;
            if (c < 3)        v = A.pt[row * 3 + c];
            else if (c < 7)   v = A.rot[row * 4 + (c - 3)];
            else if (c < 10)  v = A.scl[row * 3 + (c - 7)];
            else if (c < 11)  v = A.opa[row];
            else if (c < 59)  v = A.shs[(size_t)row * 48 + (c - 11)];
            else if (c < 187) v = A.sem[(size_t)row * 128 + (c - 59)];
            else if (c < 190) v = A.dxp[row * 3 + (c - 187)];
            else if (c < 191) v = A.te[row];
            else              v = 0.0f;     // col 191: zero pad (tpe folded into b1eff)
            sv[j] = (short)f2bf(fmaxf(v, 0.0f));
        }
    }
    return sv;
}

__global__ __launch_bounds__(256, 3) void fused_all(FusedArgs A)
{
    __shared__ u16 W1L[2][12288];           // 2 x 24 KiB double buffer

    const int tid = threadIdx.x;
    const int wave = tid >> 6;              // 0..3
    const int lane = tid & 63;
    const int q = lane >> 4, ln = lane & 15;
    const int n = A.n;
    const size_t NN = (size_t)n;

    stage24(A.W1t, W1L[0], wave, lane);     // chunk 0 DMA in flight during gather

    // each wave owns one 32-row tile (two 16-row halves); block covers 128 rows
    const int r0 = blockIdx.x * 128 + wave * 32;
    const int ra0 = min(r0 + ln, n - 1);
    const int ra1 = min(r0 + 16 + ln, n - 1);
    const int g0 = r0 + ln, g1 = r0 + 16 + ln;

    // gather x fragments once; reused by all 5 heads
    short8 xf[2][6];
#pragma unroll
    for (int kk = 0; kk < 6; ++kk) {
        int c0 = kk * 32 + q * 8;
        xf[0][kk] = gather8(A, ra0, c0);
        xf[1][kk] = gather8(A, ra1, c0);
    }

    __syncthreads();                        // chunk-0 staged (barrier drains vmcnt)

    floatx4 acc[4][2];
    floatx4 acc2[3][2];
    float out2[4][2];
    float mkb0 = 0.f, mkb1 = 0.f;

#pragma unroll 1
    for (int c = 0; c < 20; ++c) {
        const int h = c >> 2;               // head
        const int Q = c & 3;                // n-quarter (h1 cols [Q*64, Q*64+64))
        if (c + 1 < 20)
            stage24(A.W1t + (c + 1) * 12288, W1L[(c + 1) & 1], wave, lane);
        const u16* buf = W1L[c & 1];

        // ---- layer1 quarter: 64 h1 cols x 192 k x 32 rows ----
#pragma unroll
        for (int ct = 0; ct < 4; ++ct) {
            acc[ct][0] = (floatx4){0.f, 0.f, 0.f, 0.f};
            acc[ct][1] = (floatx4){0.f, 0.f, 0.f, 0.f};
        }
#pragma unroll
        for (int kk = 0; kk < 6; ++kk) {
#pragma unroll
            for (int ct = 0; ct < 4; ++ct) {
                int nl = ct * 16 + ln;
                int sw = (kk * 4 + q) ^ (ln & 7);
                short8 wf = *(const short8*)(buf + nl * 192 + (sw << 3));
                acc[ct][0] = __builtin_amdgcn_mfma_f32_16x16x32_bf16(wf, xf[0][kk], acc[ct][0], 0, 0, 0);
                acc[ct][1] = __builtin_amdgcn_mfma_f32_16x16x32_bf16(wf, xf[1][kk], acc[ct][1], 0, 0, 0);
            }
        }

        // ---- bias(+enc fold) + relu; lane(q,ln) reg r: h1[Q*64+ct*16+q*4+r][row] ----
#pragma unroll
        for (int ct = 0; ct < 4; ++ct) {
            floatx4 b4 = *(const floatx4*)(A.b1eff + h * 256 + Q * 64 + ct * 16 + q * 4);
#pragma unroll
            for (int t = 0; t < 2; ++t) {
                floatx4 v = acc[ct][t];
                v.x = fmaxf(v.x + b4.x, 0.f);
                v.y = fmaxf(v.y + b4.y, 0.f);
                v.z = fmaxf(v.z + b4.z, 0.f);
                v.w = fmaxf(v.w + b4.w, 0.f);
                acc[ct][t] = v;
            }
        }

        if (h < 4) {
            // ---- small-head layer2: f32 dot-products, no MFMA/shuffle ----
            const int od = (h == 0) ? 1 : (h == 3) ? 4 : 3;
            const int r11b = (h == 0) ? 0 : (h == 1) ? 1 : (h == 2) ? 4 : 7;
            if (Q == 0) {
#pragma unroll
                for (int m = 0; m < 4; ++m) { out2[m][0] = 0.f; out2[m][1] = 0.f; }
            }
            const float* wb = A.W2f + r11b * 256 + Q * 64 + q * 4;
#pragma unroll
            for (int n2 = 0; n2 < 4; ++n2) {
                if (n2 < od) {
#pragma unroll
                    for (int ct = 0; ct < 4; ++ct) {
                        floatx4 w4 = *(const floatx4*)(wb + n2 * 256 + ct * 16);
#pragma unroll
                        for (int t = 0; t < 2; ++t) {
                            out2[n2][t] = fmaf(acc[ct][t].x, w4.x, out2[n2][t]);
                            out2[n2][t] = fmaf(acc[ct][t].y, w4.y, out2[n2][t]);
                            out2[n2][t] = fmaf(acc[ct][t].z, w4.z, out2[n2][t]);
                            out2[n2][t] = fmaf(acc[ct][t].w, w4.w, out2[n2][t]);
                        }
                    }
                }
            }
            if (Q == 3) {
                // reduce across q-groups (lane bits 4,5); rows (ln) preserved
#pragma unroll
                for (int n2 = 0; n2 < 4; ++n2) {
#pragma unroll
                    for (int t = 0; t < 2; ++t) {
                        float v = out2[n2][t];
                        v += __shfl_xor(v, 16, 64);
                        v += __shfl_xor(v, 32, 64);
                        out2[n2][t] = v;
                    }
                }
                const float* b2h = A.b2[h];
                if (h == 0) {
                    mkb0 = 1.0f / (1.0f + expf(-(out2[0][0] + b2h[0])));
                    mkb1 = 1.0f / (1.0f + expf(-(out2[0][1] + b2h[0])));
                    if (q == 0) {
                        if (g0 < n) A.out[10 * NN + g0] = A.opa[g0];   // opacity passthrough
                        if (g1 < n) A.out[10 * NN + g1] = A.opa[g1];
                    }
                } else if (q == 0) {
#pragma unroll
                    for (int t = 0; t < 2; ++t) {
                        int grow = t ? g1 : g0;
                        float mk = t ? mkb1 : mkb0;
                        if (grow < n) {
                            if (h == 1) {
#pragma unroll
                                for (int r = 0; r < 3; ++r) {
                                    float raw = out2[r][t] + b2h[r];
                                    A.out[59 * NN + (size_t)grow * 3 + r] = raw;
                                    A.out[(size_t)grow * 3 + r] = A.pt[(size_t)grow * 3 + r] + raw * mk;
                                }
                            } else if (h == 2) {
#pragma unroll
                                for (int r = 0; r < 3; ++r) {
                                    float raw = out2[r][t] + b2h[r];
                                    A.out[3 * NN + (size_t)grow * 3 + r] = A.scl[(size_t)grow * 3 + r] + raw * mk;
                                }
                            } else {
#pragma unroll
                                for (int r = 0; r < 4; ++r) {
                                    float raw = out2[r][t] + b2h[r];
                                    A.out[6 * NN + (size_t)grow * 4 + r] = A.rot[(size_t)grow * 4 + r] + raw * mk;
                                }
                            }
                        }
                    }
                }
            }
        } else {
            // ---- shs head layer2: MFMA with shuffled B-fragment ----
            if (Q == 0) {
#pragma unroll
                for (int mt = 0; mt < 3; ++mt) {
                    acc2[mt][0] = (floatx4){0.f, 0.f, 0.f, 0.f};
                    acc2[mt][1] = (floatx4){0.f, 0.f, 0.f, 0.f};
                }
            }
            const u16* w2th = A.W2t + 64 * 256;
#pragma unroll
            for (int ks = 0; ks < 2; ++ks) {
                int ksg = Q * 2 + ks;
                short8 a2[3];
#pragma unroll
                for (int mt = 0; mt < 3; ++mt)
                    a2[mt] = *(const short8*)(w2th + (mt * 16 + ln) * 256 + ksg * 32 + q * 8);
#pragma unroll
                for (int t = 0; t < 2; ++t) {
                    short8 bfrag;
#pragma unroll
                    for (int j = 0; j < 8; ++j) {
                        int idx = (((q * 2 + (j >> 2)) & 3) << 4) | ln;
                        float v0 = __shfl(acc[ks * 2 + 0][t][j & 3], idx, 64);
                        float v1 = __shfl(acc[ks * 2 + 1][t][j & 3], idx, 64);
                        bfrag[j] = (short)f2bf((q >> 1) ? v1 : v0);
                    }
#pragma unroll
                    for (int mt = 0; mt < 3; ++mt)
                        acc2[mt][t] = __builtin_amdgcn_mfma_f32_16x16x32_bf16(a2[mt], bfrag, acc2[mt][t], 0, 0, 0);
                }
            }
            if (Q == 3) {
                const float* b2h = A.b2[4];
#pragma unroll
                for (int t = 0; t < 2; ++t) {
                    int grow = t ? g1 : g0;
                    float mk = t ? mkb1 : mkb0;
                    if (grow < n) {
#pragma unroll
                        for (int mt = 0; mt < 3; ++mt) {
                            int n2b = mt * 16 + q * 4;
                            floatx4 b2v = *(const floatx4*)(b2h + n2b);
                            floatx4 raw = acc2[mt][t] + b2v;
                            *(floatx4*)(A.out + 62 * NN + (size_t)grow * 48 + n2b) = raw;
                            floatx4 s = *(const floatx4*)(A.shs + (size_t)grow * 48 + n2b);
                            *(floatx4*)(A.out + 11 * NN + (size_t)grow * 48 + n2b) = s + raw * mk;
                        }
                    }
                }
            }
        }

        __syncthreads();   // drains next-chunk DMA; all waves done with buf[c&1]
    }
}

extern "C" void kernel_launch(void* const* d_in, const int* in_sizes, int n_in,
                              void* d_out, int out_size, void* d_ws, size_t ws_size,
                              hipStream_t stream)
{
    const float* opa  = (const float*)d_in[0];
    const float* shs  = (const float*)d_in[1];
    const float* te   = (const float*)d_in[2];
    const float* sem  = (const float*)d_in[3];
    const float* pt   = (const float*)d_in[4];
    const float* scl  = (const float*)d_in[5];
    const float* rot  = (const float*)d_in[6];
    const float* dx   = (const float*)d_in[7];

    WPtrs p;
    p.w1[0] = (const float*)d_in[8];  p.w2[0] = (const float*)d_in[10]; p.b1[0] = (const float*)d_in[9];
    p.w1[1] = (const float*)d_in[12]; p.w2[1] = (const float*)d_in[14]; p.b1[1] = (const float*)d_in[13];
    p.w1[2] = (const float*)d_in[16]; p.w2[2] = (const float*)d_in[18]; p.b1[2] = (const float*)d_in[17];
    p.w1[3] = (const float*)d_in[20]; p.w2[3] = (const float*)d_in[22]; p.b1[3] = (const float*)d_in[21];
    p.w1[4] = (const float*)d_in[24]; p.w2[4] = (const float*)d_in[26]; p.b1[4] = (const float*)d_in[25];

    const int n = in_sizes[0];               // 200000

    char* ws = (char*)d_ws;
    u16*   W1t   = (u16*)ws;                           // 5*49152 bf16 = 491520 B
    u16*   W2t   = (u16*)(ws + 491520);                // 112*256 bf16 = 57344 B
    float* W2f   = (float*)(ws + 491520 + 57344);      // 11*256 f32 = 11264 B
    float* b1eff = (float*)(ws + 491520 + 57344 + 11264); // 5*256 f32 = 5120 B

    prep_weights<<<173, 256, 0, stream>>>(p, te, W1t, W2t, W2f, b1eff);

    FusedArgs A;
    A.W1t = W1t; A.W2t = W2t; A.W2f = W2f; A.b1eff = b1eff;
    A.b2[0] = (const float*)d_in[11];
    A.b2[1] = (const float*)d_in[15];
    A.b2[2] = (const float*)d_in[19];
    A.b2[3] = (const float*)d_in[23];
    A.b2[4] = (const float*)d_in[27];
    A.opa = opa; A.shs = shs; A.te = te; A.sem = sem;
    A.pt = pt; A.scl = scl; A.rot = rot; A.dxp = dx;
    A.out = (float*)d_out; A.n = n;

    int grid = (n + 127) / 128;              // 1563 blocks x 4 waves x 32 rows
    fused_all<<<grid, 256, 0, stream>>>(A);
}